// Round 3
// baseline (273.946 us; speedup 1.0000x reference)
//
#include <hip/hip_runtime.h>
#include <cmath>

// Problem constants (from setup_inputs)
constexpr int B     = 32;
constexpr int L     = 2048;
constexpr int D_CTX = 512;
constexpr int D_Q   = 1024;
constexpr int H     = 256;
constexpr int PRUNE_L = -3;
constexpr int PRUNE_R = 3;
constexpr int W = PRUNE_R - PRUNE_L + 1;  // 7-position window

// ---------------------------------------------------------------------------
// Fully fused kernel: one block per batch row, 1024 threads.
//   1. h    = tanh(q @ Wq + bq); qpre = q @ W1[D_CTX:,:] + b1   (interleaved)
//   2. alpha/beta/kappa/center from h @ Ws + bs (wave-0 shuffle reduce)
//   3. for each of 7 window positions: score = tanh(ctx_row @ W1[:D_CTX] + qpre) @ W2 + b2
//      post[t] = exp(score)*alpha*exp(-beta*diff^2)
//   4. normalize, zero+scatter p_ctx row, expected_ctx = 7-term gather.
// All intermediates live in LDS; no workspace traffic, single launch.
//
// Thread layout for matmuls: jg = tid&63 (float4 of 4 consecutive hidden units,
// 16B coalesced weight loads), kc = tid>>6 (16 K-chunks). K-chunk partials are
// reduced by 256 threads each summing 16 floats at stride 256 (conflict-free).
// ---------------------------------------------------------------------------
__global__ __launch_bounds__(1024) void fused_kernel(
    const float* __restrict__ query,      // [B, D_Q]
    const float* __restrict__ ctx,        // [B, L, D_CTX]
    const float* __restrict__ kappa_prev, // [B, 1]
    const float* __restrict__ Wq,         // [D_Q, H]
    const float* __restrict__ bq,         // [H]
    const float* __restrict__ Ws,         // [H, 3]
    const float* __restrict__ bs,         // [3]
    const float* __restrict__ W1,         // [D_CTX+D_Q, H]
    const float* __restrict__ b1,         // [H]
    const float* __restrict__ W2,         // [H, 1]
    const float* __restrict__ b2,         // [1]
    float* __restrict__ out_e,            // [B, D_CTX]
    float* __restrict__ out_p)            // [B, L]
{
    const int b   = blockIdx.x;
    const int tid = threadIdx.x;
    const int jg  = tid & 63;   // float4 column group: j = 4*jg .. 4*jg+3
    const int kc  = tid >> 6;   // K-chunk index 0..15

    __shared__ float  q_sh[D_Q];        // 4 KB
    __shared__ float4 partA[16][64];    // 16 KB
    __shared__ float4 partB[16][64];    // 16 KB
    __shared__ float  h_sh[H];          // 1 KB
    __shared__ float  qpre[H];          // 1 KB  (q-half pre-activation + b1)
    __shared__ float  red[H];           // 1 KB
    __shared__ float  c_sh[D_CTX];      // 2 KB
    __shared__ float  post_sh[W];
    __shared__ float  p_sh[W];
    __shared__ float  stats_sh[4];      // alpha, beta, kappa, center

    // ---- stage query ----------------------------------------------------
    if (tid < D_Q / 4)
        ((float4*)q_sh)[tid] = ((const float4*)(query + (size_t)b * D_Q))[tid];
    __syncthreads();

    // ---- interleaved K=1024 matmuls: Wq (-> h) and W1[D_CTX:,:] (-> qpre)
    {
        const float4* WqV = (const float4*)Wq;
        const float4* W1V = (const float4*)(W1 + (size_t)D_CTX * H);
        float4 a = make_float4(0.f, 0.f, 0.f, 0.f);
        float4 c = make_float4(0.f, 0.f, 0.f, 0.f);
        const int k0 = kc * 64;
#pragma unroll 8
        for (int k = k0; k < k0 + 64; ++k) {
            const float  qk = q_sh[k];
            const float4 wa = WqV[k * 64 + jg];
            const float4 wb = W1V[k * 64 + jg];
            a.x += qk * wa.x; a.y += qk * wa.y; a.z += qk * wa.z; a.w += qk * wa.w;
            c.x += qk * wb.x; c.y += qk * wb.y; c.z += qk * wb.z; c.w += qk * wb.w;
        }
        partA[kc][jg] = a;
        partB[kc][jg] = c;
    }
    __syncthreads();
    if (tid < H) {
        const float* pa = (const float*)partA;  // pa[kc*256 + j]
        const float* pb = (const float*)partB;
        float sa = 0.f, sb = 0.f;
#pragma unroll
        for (int k2 = 0; k2 < 16; ++k2) { sa += pa[k2 * 256 + tid]; sb += pb[k2 * 256 + tid]; }
        h_sh[tid] = tanhf(sa + bq[tid]);
        qpre[tid] = sb + b1[tid];
    }
    __syncthreads();

    // ---- stats: wave 0 shuffle-reduce h @ Ws ----------------------------
    if (tid < 64) {
        float s0 = 0.f, s1 = 0.f, s2 = 0.f;
#pragma unroll
        for (int i = 0; i < 4; ++i) {
            const int   j  = tid + 64 * i;
            const float hv = h_sh[j];
            s0 += hv * Ws[j * 3 + 0];
            s1 += hv * Ws[j * 3 + 1];
            s2 += hv * Ws[j * 3 + 2];
        }
        for (int off = 32; off > 0; off >>= 1) {
            s0 += __shfl_down(s0, off);
            s1 += __shfl_down(s1, off);
            s2 += __shfl_down(s2, off);
        }
        if (tid == 0) {
            const float alpha = expf(s0 + bs[0]);
            const float beta  = expf(s1 + bs[1]);
            const float kappa = expf(s2 + bs[2]) + kappa_prev[b];
            stats_sh[0] = alpha;
            stats_sh[1] = beta;
            stats_sh[2] = kappa;
            stats_sh[3] = rintf(kappa);  // round-half-even == jnp.round
        }
    }
    __syncthreads();
    const float alpha  = stats_sh[0];
    const float beta   = stats_sh[1];
    const float kappa  = stats_sh[2];
    const int   center = (int)stats_sh[3];

    // ---- 7 window positions: ctx-half matmul + score --------------------
    for (int t = 0; t < W; ++t) {
        const int  l     = center + PRUNE_L + t;
        const bool valid = (l >= 0 && l < L);   // block-uniform

        if (valid && tid < D_CTX / 4)
            ((float4*)c_sh)[tid] =
                ((const float4*)(ctx + ((size_t)b * L + (size_t)l) * D_CTX))[tid];
        __syncthreads();

        if (valid) {
            const float4* W1V = (const float4*)W1;  // rows [0, D_CTX)
            float4 a = make_float4(0.f, 0.f, 0.f, 0.f);
            const int k0 = kc * 32;
#pragma unroll 8
            for (int k = k0; k < k0 + 32; ++k) {
                const float  ck = c_sh[k];
                const float4 w  = W1V[k * 64 + jg];
                a.x += ck * w.x; a.y += ck * w.y; a.z += ck * w.z; a.w += ck * w.w;
            }
            partA[kc][jg] = a;
        }
        __syncthreads();

        if (valid && tid < H) {
            const float* pa = (const float*)partA;
            float s = 0.f;
#pragma unroll
            for (int k2 = 0; k2 < 16; ++k2) s += pa[k2 * 256 + tid];
            red[tid] = tanhf(s + qpre[tid]) * W2[tid];
        }
        __syncthreads();

        if (tid < 64) {
            float s = valid ? (red[tid] + red[tid + 64] + red[tid + 128] + red[tid + 192])
                            : 0.f;
            for (int off = 32; off > 0; off >>= 1) s += __shfl_down(s, off);
            if (tid == 0) {
                if (valid) {
                    const float diff = (float)l - kappa;
                    post_sh[t] = expf(s + b2[0]) * alpha * expf(-beta * diff * diff);
                } else {
                    post_sh[t] = 0.f;
                }
            }
        }
        // next iteration's leading __syncthreads guards c_sh/partA/red reuse
    }
    __syncthreads();

    // ---- normalize ------------------------------------------------------
    if (tid == 0) {
        float sum = 0.f;
        for (int t = 0; t < W; ++t) sum += post_sh[t];
        const float inv = 1.0f / sum;  // sum==0 -> NaN, same as reference
        for (int t = 0; t < W; ++t) p_sh[t] = post_sh[t] * inv;
    }
    __syncthreads();

    // ---- p_ctx row: zero-fill (d_out poisoned) then scatter window ------
    float4* prow = (float4*)(out_p + (size_t)b * L);
    if (tid < L / 4) prow[tid] = make_float4(0.f, 0.f, 0.f, 0.f);
    __syncthreads();
    if (tid < W) {
        const int l = center + PRUNE_L + tid;
        if (l >= 0 && l < L) out_p[(size_t)b * L + l] = p_sh[tid];
    }

    // ---- expected_ctx: 7-term weighted float4 gather --------------------
    if (tid < D_CTX / 4) {
        float4 acc = make_float4(0.f, 0.f, 0.f, 0.f);
#pragma unroll
        for (int t = 0; t < W; ++t) {
            const int l = center + PRUNE_L + t;
            if (l >= 0 && l < L) {
                const float4 cv =
                    ((const float4*)(ctx + ((size_t)b * L + (size_t)l) * D_CTX))[tid];
                const float p = p_sh[t];
                acc.x += p * cv.x; acc.y += p * cv.y;
                acc.z += p * cv.z; acc.w += p * cv.w;
            }
        }
        ((float4*)(out_e + (size_t)b * D_CTX))[tid] = acc;
    }
}

extern "C" void kernel_launch(void* const* d_in, const int* in_sizes, int n_in,
                              void* d_out, int out_size, void* d_ws, size_t ws_size,
                              hipStream_t stream) {
    const float* query      = (const float*)d_in[0];
    const float* ctx        = (const float*)d_in[1];
    const float* kappa_prev = (const float*)d_in[2];
    const float* Wq         = (const float*)d_in[3];
    const float* bq         = (const float*)d_in[4];
    const float* Ws         = (const float*)d_in[5];
    const float* bs         = (const float*)d_in[6];
    const float* W1         = (const float*)d_in[7];
    const float* b1         = (const float*)d_in[8];
    const float* W2         = (const float*)d_in[9];
    const float* b2         = (const float*)d_in[10];

    float* out   = (float*)d_out;
    float* out_e = out;              // [B, D_CTX]
    float* out_p = out + B * D_CTX;  // [B, L]

    fused_kernel<<<B, 1024, 0, stream>>>(query, ctx, kappa_prev, Wq, bq, Ws, bs,
                                         W1, b1, W2, b2, out_e, out_p);
}

// Round 4
// 198.498 us; speedup vs baseline: 1.3801x; 1.3801x over previous
//
#include <hip/hip_runtime.h>
#include <cmath>

// Problem constants (from setup_inputs)
constexpr int B     = 32;
constexpr int L     = 2048;
constexpr int D_CTX = 512;
constexpr int D_Q   = 1024;
constexpr int H     = 256;
constexpr int PRUNE_L = -3;
constexpr int PRUNE_R = 3;
constexpr int W = PRUNE_R - PRUNE_L + 1;  // 7-position window
constexpr int KC = 16;                    // K-chunks for the query matmuls

// ---------------------------------------------------------------------------
// Kernel A1: K-split partials of BOTH query matmuls.
//   partQ[b,kc,j] = sum_{k in chunk} q[k] * Wq[k,j]
//   part1[b,kc,j] = sum_{k in chunk} q[k] * W1[D_CTX+k,j]
// grid = (KC, B) = 512 blocks, block = 256 (thread j). Weight loads are
// 4B-coalesced across j; 128 independent loads per thread -> high MLP, and
// 512 blocks spread the cold-HBM weight fetch over all 8 XCDs.
// ---------------------------------------------------------------------------
__global__ __launch_bounds__(256) void partial_kernel(
    const float* __restrict__ query,  // [B, D_Q]
    const float* __restrict__ Wq,     // [D_Q, H]
    const float* __restrict__ W1,     // [D_CTX+D_Q, H]
    float* __restrict__ partQ,        // [B, KC, H]
    float* __restrict__ part1)        // [B, KC, H]
{
    const int kc = blockIdx.x;
    const int b  = blockIdx.y;
    const int j  = threadIdx.x;
    const int k0 = kc * (D_Q / KC);   // 64-k chunk

    __shared__ float q_sh[D_Q / KC];
    if (j < D_Q / KC) q_sh[j] = query[b * D_Q + k0 + j];
    __syncthreads();

    const float* WqR = Wq + (size_t)k0 * H + j;
    const float* W1R = W1 + ((size_t)D_CTX + k0) * H + j;
    float accQ = 0.f, acc1 = 0.f;
#pragma unroll 16
    for (int k = 0; k < D_Q / KC; ++k) {
        const float qk = q_sh[k];
        accQ += qk * WqR[(size_t)k * H];
        acc1 += qk * W1R[(size_t)k * H];
    }
    partQ[((size_t)b * KC + kc) * H + j] = accQ;
    part1[((size_t)b * KC + kc) * H + j] = acc1;
}

// ---------------------------------------------------------------------------
// Kernel A2: reduce partials -> h, qpre; compute alpha/beta/kappa/center.
// grid = B, block = 256.
// ---------------------------------------------------------------------------
__global__ __launch_bounds__(256) void stats_kernel(
    const float* __restrict__ kappa_prev, // [B, 1]
    const float* __restrict__ bq,         // [H]
    const float* __restrict__ Ws,         // [H, 3]
    const float* __restrict__ bs,         // [3]
    const float* __restrict__ b1,         // [H]
    const float* __restrict__ partQ,      // [B, KC, H]
    const float* __restrict__ part1,      // [B, KC, H]
    float* __restrict__ stats,            // [B, 4] = {alpha, beta, kappa, center}
    float* __restrict__ qpre)             // [B, H]  (q-half preact + b1)
{
    const int b = blockIdx.x;
    const int j = threadIdx.x;

    float sq = 0.f, s1 = 0.f;
#pragma unroll
    for (int kc = 0; kc < KC; ++kc) {
        sq += partQ[((size_t)b * KC + kc) * H + j];
        s1 += part1[((size_t)b * KC + kc) * H + j];
    }
    __shared__ float h_sh[H];
    h_sh[j] = tanhf(sq + bq[j]);
    qpre[(size_t)b * H + j] = s1 + b1[j];
    __syncthreads();

    if (j < 64) {
        float s0 = 0.f, s1r = 0.f, s2 = 0.f;
#pragma unroll
        for (int i = 0; i < 4; ++i) {
            const int   jj = j + 64 * i;
            const float hv = h_sh[jj];
            s0  += hv * Ws[jj * 3 + 0];
            s1r += hv * Ws[jj * 3 + 1];
            s2  += hv * Ws[jj * 3 + 2];
        }
        for (int off = 32; off > 0; off >>= 1) {
            s0  += __shfl_down(s0, off);
            s1r += __shfl_down(s1r, off);
            s2  += __shfl_down(s2, off);
        }
        if (j == 0) {
            const float alpha = expf(s0 + bs[0]);
            const float beta  = expf(s1r + bs[1]);
            const float kappa = expf(s2 + bs[2]) + kappa_prev[b];
            stats[b * 4 + 0] = alpha;
            stats[b * 4 + 1] = beta;
            stats[b * 4 + 2] = kappa;
            stats[b * 4 + 3] = rintf(kappa);  // round-half-even == jnp.round
        }
    }
}

// ---------------------------------------------------------------------------
// Kernel B: MLP score + unnormalized posterior at the 7 window positions.
//   score = tanh(ctx_row @ W1[:D_CTX] + qpre) @ W2 + b2
//   post  = exp(score) * alpha * exp(-beta * (l-kappa)^2)
// grid = (W, B) = 224 blocks, block = 512: jg = tid&63 (float4 j),
// kc = tid>>6 (8 chunks of 64 k).
// ---------------------------------------------------------------------------
__global__ __launch_bounds__(512) void score_kernel(
    const float* __restrict__ ctx,    // [B, L, D_CTX]
    const float* __restrict__ W1,     // [D_CTX+D_Q, H]; uses rows [0, D_CTX)
    const float* __restrict__ W2,     // [H, 1]
    const float* __restrict__ b2,     // [1]
    const float* __restrict__ stats,  // [B, 4]
    const float* __restrict__ qpre,   // [B, H]
    float* __restrict__ post)         // [B, W]
{
    const int t   = blockIdx.x;  // window slot 0..6
    const int b   = blockIdx.y;
    const int tid = threadIdx.x;
    const int jg  = tid & 63;
    const int kc  = tid >> 6;    // 0..7

    const float alpha  = stats[b * 4 + 0];
    const float beta   = stats[b * 4 + 1];
    const float kappa  = stats[b * 4 + 2];
    const int   center = (int)stats[b * 4 + 3];
    const int   l      = center + PRUNE_L + t;

    if (l < 0 || l >= L) {               // block-uniform branch
        if (tid == 0) post[b * W + t] = 0.0f;
        return;
    }

    __shared__ float  c_sh[D_CTX];       // 2 KB
    __shared__ float4 part[8][64];       // 8 KB
    __shared__ float  red[H];            // 1 KB

    const float4* ctx4 = (const float4*)(ctx + ((size_t)b * L + (size_t)l) * D_CTX);
    if (tid < D_CTX / 4) ((float4*)c_sh)[tid] = ctx4[tid];
    __syncthreads();

    const float4* Wv = (const float4*)W1;
    float4 acc = make_float4(0.f, 0.f, 0.f, 0.f);
    const int k0 = kc * 64;
#pragma unroll 8
    for (int k = k0; k < k0 + 64; ++k) {
        const float  ck = c_sh[k];
        const float4 w  = Wv[k * 64 + jg];
        acc.x += ck * w.x; acc.y += ck * w.y;
        acc.z += ck * w.z; acc.w += ck * w.w;
    }
    part[kc][jg] = acc;
    __syncthreads();
    for (int s = 4; s > 0; s >>= 1) {    // 8-way K-chunk reduce
        if (kc < s) {
            float4 a = part[kc][jg], c = part[kc + s][jg];
            a.x += c.x; a.y += c.y; a.z += c.z; a.w += c.w;
            part[kc][jg] = a;
        }
        __syncthreads();
    }
    if (tid < H) {
        const float pre = ((const float*)part)[tid] + qpre[(size_t)b * H + tid];
        red[tid] = tanhf(pre) * W2[tid];
    }
    __syncthreads();
    for (int s = H / 2; s > 0; s >>= 1) {
        if (tid < s) red[tid] += red[tid + s];
        __syncthreads();
    }
    if (tid == 0) {
        const float score = red[0] + b2[0];
        const float diff  = (float)l - kappa;
        post[b * W + t] = expf(score) * alpha * expf(-beta * diff * diff);
    }
}

// ---------------------------------------------------------------------------
// Kernel C: normalize posterior, write p_ctx (zeros + 7-entry scatter) and
// expected_ctx = sum_t p_t * ctx[b, l_t, :].
// grid = B, block = 256
// ---------------------------------------------------------------------------
__global__ __launch_bounds__(256) void combine_kernel(
    const float* __restrict__ ctx,    // [B, L, D_CTX]
    const float* __restrict__ stats,  // [B, 4]
    const float* __restrict__ post,   // [B, W]
    float* __restrict__ out_e,        // [B, D_CTX]
    float* __restrict__ out_p)        // [B, L]
{
    const int b = blockIdx.x;
    const int j = threadIdx.x;

    __shared__ float p_sh[W];
    __shared__ int   l_sh[W];
    if (j == 0) {
        const int center = (int)stats[b * 4 + 3];
        float sum = 0.0f;
        for (int t = 0; t < W; ++t) sum += post[b * W + t];
        const float inv = 1.0f / sum;  // sum==0 -> NaN, same as reference
        for (int t = 0; t < W; ++t) {
            p_sh[t] = post[b * W + t] * inv;
            l_sh[t] = center + PRUNE_L + t;
        }
    }
    __syncthreads();

    // p_ctx row: zero-fill (d_out is poisoned) then scatter the window
    float4* prow = (float4*)(out_p + (size_t)b * L);
    const float4 z = make_float4(0.f, 0.f, 0.f, 0.f);
    prow[j]       = z;                  // 2048 floats = 512 float4, 2 per thread
    prow[j + 256] = z;
    __syncthreads();
    if (j < W) {
        const int l = l_sh[j];
        if (l >= 0 && l < L) out_p[(size_t)b * L + l] = p_sh[j];
    }

    // expected_ctx: 7-term weighted float4 gather (128 float4 = 512 dims)
    if (j < D_CTX / 4) {
        float4 acc = make_float4(0.f, 0.f, 0.f, 0.f);
#pragma unroll
        for (int t = 0; t < W; ++t) {
            const int l = l_sh[t];
            if (l >= 0 && l < L) {
                const float4 c = ((const float4*)(ctx + ((size_t)b * L + (size_t)l) * D_CTX))[j];
                const float  p = p_sh[t];
                acc.x += p * c.x; acc.y += p * c.y;
                acc.z += p * c.z; acc.w += p * c.w;
            }
        }
        ((float4*)(out_e + (size_t)b * D_CTX))[j] = acc;
    }
}

extern "C" void kernel_launch(void* const* d_in, const int* in_sizes, int n_in,
                              void* d_out, int out_size, void* d_ws, size_t ws_size,
                              hipStream_t stream) {
    const float* query      = (const float*)d_in[0];
    const float* ctx        = (const float*)d_in[1];
    const float* kappa_prev = (const float*)d_in[2];
    const float* Wq         = (const float*)d_in[3];
    const float* bq         = (const float*)d_in[4];
    const float* Ws         = (const float*)d_in[5];
    const float* bs         = (const float*)d_in[6];
    const float* W1         = (const float*)d_in[7];
    const float* b1         = (const float*)d_in[8];
    const float* W2         = (const float*)d_in[9];
    const float* b2         = (const float*)d_in[10];

    float* out   = (float*)d_out;
    float* out_e = out;              // [B, D_CTX]
    float* out_p = out + B * D_CTX;  // [B, L]

    // Workspace layout (all 16B-aligned):
    float* stats = (float*)d_ws;               // [B, 4]          = 128 floats
    float* qpre  = stats + B * 4;              // [B, H]          = 8192
    float* post  = qpre + B * H;               // [B, W]          = 224
    float* partQ = post + B * W + 8;           // [B, KC, H], +8 pads to 16B
    float* part1 = partQ + B * KC * H;         // [B, KC, H]

    partial_kernel<<<dim3(KC, B), 256, 0, stream>>>(query, Wq, W1, partQ, part1);
    stats_kernel<<<B, 256, 0, stream>>>(kappa_prev, bq, Ws, bs, b1,
                                        partQ, part1, stats, qpre);
    score_kernel<<<dim3(W, B), 512, 0, stream>>>(ctx, W1, W2, b2, stats, qpre, post);
    combine_kernel<<<B, 256, 0, stream>>>(ctx, stats, post, out_e, out_p);
}